// Round 2
// baseline (87.759 us; speedup 1.0000x reference)
//
#include <hip/hip_runtime.h>
#include <hip/hip_bf16.h>
#include <math.h>

// Problem constants
#define Bn    8
#define Sn    8
#define CINc  64
#define Hh    32
#define Wwi   32
#define COUTc 128
#define PWc   73728
#define Pc    73856
#define WOc   30
#define NPIX  900      // 30*30 per (b,s)
#define GPIX  7200     // B*NPIX per s
#define KTOT  576      // CIN*3*3
#define NSTEP 9        // K-steps: one r = (ky,kx) each, 64 ci per step
#define PIXT  64
#define NTILES 113     // ceil(7200/64)

typedef __bf16 bf16;
typedef bf16  bf16x8 __attribute__((ext_vector_type(8)));
typedef float f32x4  __attribute__((ext_vector_type(4)));

__device__ __forceinline__ float softplus_f(float x) {
    return fmaxf(x, 0.f) + log1pf(expf(-fabsf(x)));
}

__device__ __forceinline__ unsigned int pack2(float a, float b) {
    unsigned short ua = __builtin_bit_cast(unsigned short, (bf16)a);
    unsigned short ub = __builtin_bit_cast(unsigned short, (bf16)b);
    return ((unsigned int)ub << 16) | (unsigned int)ua;
}

// ---------------------------------------------------------------------------
// Kernel A: sample weights (r-major layout for conv) + biases + KL partials.
// wq[((s*9 + r)*128 + co)*64 + ci] = mu_w[p] + softplus(rho_w[p])*e[s*P + p]
// with p = co*576 + ci*9 + r  (OIHW flatten).
// ---------------------------------------------------------------------------
__global__ __launch_bounds__(256) void prep_kernel(
        const float* __restrict__ e,
        const float* __restrict__ mu_w, const float* __restrict__ rho_w,
        const float* __restrict__ mu_b, const float* __restrict__ rho_b,
        bf16* __restrict__ wq, float* __restrict__ bq,
        float* __restrict__ partials) {
    int i = blockIdx.x * blockDim.x + threadIdx.x;
    float ls = 0.f, sq = 0.f;
    if (i < PWc) {
        int co  = i / 576;
        int rem = i - co * 576;
        int ci  = rem / 9;
        int r   = rem - ci * 9;
        int dst = (r * COUTc + co) * 64 + ci;
        float sig = softplus_f(rho_w[i]);
        ls = logf(sig);
        float mu = mu_w[i];
        #pragma unroll
        for (int s = 0; s < Sn; ++s) {
            float wv = fmaf(sig, e[s * Pc + i], mu);
            wq[s * PWc + dst] = (bf16)wv;
            sq += wv * wv;
        }
    } else if (i < Pc) {
        int c = i - PWc;
        float sig = softplus_f(rho_b[c]);
        ls = logf(sig);
        float mu = mu_b[c];
        #pragma unroll
        for (int s = 0; s < Sn; ++s) {
            float bv = fmaf(sig, e[s * Pc + i], mu);
            bq[s * COUTc + c] = bv;
            sq += bv * bv;
        }
    }
    #pragma unroll
    for (int off = 32; off > 0; off >>= 1) {
        ls += __shfl_down(ls, off);
        sq += __shfl_down(sq, off);
    }
    __shared__ float sls[4], ssq[4];
    int lane = threadIdx.x & 63, wid = threadIdx.x >> 6;
    if (lane == 0) { sls[wid] = ls; ssq[wid] = sq; }
    __syncthreads();
    if (threadIdx.x == 0) {
        atomicAdd(&partials[0], sls[0] + sls[1] + sls[2] + sls[3]);
        atomicAdd(&partials[1], ssq[0] + ssq[1] + ssq[2] + ssq[3]);
    }
}

__global__ void finalize_kl(const float* __restrict__ partials,
                            float* __restrict__ out_kl) {
    float kl = -partials[0] + 0.91893853320467274f * (float)(PWc + COUTc)
             + 0.5f * partials[1];
    *out_kl = kl;
}

// ---------------------------------------------------------------------------
// Kernel C: implicit-GEMM conv, r-major K order, BK=64 (one r per step).
// Block: one s, 64 pixels, 128 co; 4 waves 2x2 (wave tile 64co x 32pix).
// LDS: Wl [128][64] bf16, Xl [64][64] bf16, XOR-swizzled 16B blocks
// (block ^= row&7) -> conflict-free b128 reads/writes. 24 KB total.
// Prefetch for step t+1 issued in compute phase of step t.
// ---------------------------------------------------------------------------
__global__ __launch_bounds__(256, 4) void conv_mfma(
        const float* __restrict__ xg, const bf16* __restrict__ wq,
        const float* __restrict__ bq, float* __restrict__ out) {
    const int s    = blockIdx.y;
    const int tile = blockIdx.x;
    const int t    = threadIdx.x;
    const int lane = t & 63;
    const int wid  = t >> 6;
    const int wr   = wid >> 1;   // co half (0/1)
    const int wc   = wid & 1;    // pix half (0/1)

    __shared__ bf16 Wl[COUTc * 64];   // 16 KB
    __shared__ bf16 Xl[PIXT * 64];    // 8 KB

    // ---- X gather: thread owns pix = t&63, ci chunk c2 = t>>6 (16 ci)
    const int pixl = t & 63;
    const int c2   = t >> 6;          // wave id, uniform per wave
    int g = tile * PIXT + pixl;
    if (g >= GPIX) g = GPIX - 1;      // clamp; garbage columns discarded at store
    const int bb = g / NPIX;
    const int rr = g - bb * NPIX;
    const int oy = rr / WOc;
    const int ox = rr - oy * WOc;
    const float* xpix = xg + ((size_t)(bb * Sn + s) << 16) + oy * Wwi + ox
                           + (size_t)c2 * 16 * 1024;
    bf16* xw0 = Xl + pixl * 64 + ((((c2 << 1) + 0) ^ (pixl & 7)) << 3);
    bf16* xw1 = Xl + pixl * 64 + ((((c2 << 1) + 1) ^ (pixl & 7)) << 3);

    // ---- W stage: thread owns cio = t&7 (16B block), rows co0 + 32*i
    const int cio = t & 7;
    const int co0 = t >> 3;           // 0..31
    const int wslot = (cio ^ (co0 & 7)) << 3;  // co&7 == co0&7 for co0+32i

    // ---- frag read addressing (loop-invariant)
    const int arow = lane & 15;
    const int sb   = lane >> 4;       // 0..3
    const int sx   = lane & 7;

    f32x4 acc[4][2];
    #pragma unroll
    for (int i = 0; i < 4; ++i)
        #pragma unroll
        for (int j = 0; j < 2; ++j)
            acc[i][j] = f32x4{0.f, 0.f, 0.f, 0.f};

    // ---- prologue: prefetch step 0
    float xr[16];
    uint4 wv4[4];
    {
        const bf16* wsp = wq + (size_t)(s * NSTEP) * (COUTc * 64);
        #pragma unroll
        for (int i = 0; i < 4; ++i)
            wv4[i] = *reinterpret_cast<const uint4*>(wsp + (co0 + 32 * i) * 64 + (cio << 3));
        #pragma unroll
        for (int j = 0; j < 16; ++j)
            xr[j] = xpix[j * 1024];
    }

    for (int step = 0; step < NSTEP; ++step) {
        __syncthreads();   // previous step's frag reads complete (WAR)

        // stage tiles from prefetched regs
        #pragma unroll
        for (int i = 0; i < 4; ++i)
            *reinterpret_cast<uint4*>(Wl + (co0 + 32 * i) * 64 + wslot) = wv4[i];
        uint4 v0, v1;
        v0.x = pack2(xr[0], xr[1]);  v0.y = pack2(xr[2], xr[3]);
        v0.z = pack2(xr[4], xr[5]);  v0.w = pack2(xr[6], xr[7]);
        v1.x = pack2(xr[8], xr[9]);  v1.y = pack2(xr[10], xr[11]);
        v1.z = pack2(xr[12], xr[13]); v1.w = pack2(xr[14], xr[15]);
        *reinterpret_cast<uint4*>(xw0) = v0;
        *reinterpret_cast<uint4*>(xw1) = v1;

        __syncthreads();   // tiles visible

        // prefetch step+1 during compute (drained at next barrier, hidden)
        if (step < NSTEP - 1) {
            int rn = step + 1;
            int ky = rn / 3;
            int roff = ky * Wwi + (rn - ky * 3);
            const bf16* wsp = wq + (size_t)(s * NSTEP + rn) * (COUTc * 64);
            #pragma unroll
            for (int i = 0; i < 4; ++i)
                wv4[i] = *reinterpret_cast<const uint4*>(wsp + (co0 + 32 * i) * 64 + (cio << 3));
            #pragma unroll
            for (int j = 0; j < 16; ++j)
                xr[j] = xpix[roff + j * 1024];
        }

        // fragments + MFMA: K=64 as two k-chunks of 32
        #pragma unroll
        for (int kk = 0; kk < 2; ++kk) {
            const int slot = (((kk << 2) + sb) ^ sx) << 3;
            bf16x8 af[4], bfv[2];
            #pragma unroll
            for (int fm = 0; fm < 4; ++fm)
                af[fm] = *reinterpret_cast<const bf16x8*>(
                    Wl + (wr * 64 + fm * 16 + arow) * 64 + slot);
            #pragma unroll
            for (int fn = 0; fn < 2; ++fn)
                bfv[fn] = *reinterpret_cast<const bf16x8*>(
                    Xl + (wc * 32 + fn * 16 + arow) * 64 + slot);
            #pragma unroll
            for (int fm = 0; fm < 4; ++fm)
                #pragma unroll
                for (int fn = 0; fn < 2; ++fn)
                    acc[fm][fn] = __builtin_amdgcn_mfma_f32_16x16x32_bf16(
                        af[fm], bfv[fn], acc[fm][fn], 0, 0, 0);
        }
    }

    // epilogue: D mapping col(pix)=lane&15, row(co)=(lane>>4)*4+reg
    float bias[4][4];
    #pragma unroll
    for (int fm = 0; fm < 4; ++fm)
        #pragma unroll
        for (int j = 0; j < 4; ++j)
            bias[fm][j] = bq[s * COUTc + wr * 64 + fm * 16 + (lane >> 4) * 4 + j];

    #pragma unroll
    for (int fn = 0; fn < 2; ++fn) {
        int pl = wc * 32 + fn * 16 + (lane & 15);
        int gg = tile * PIXT + pl;
        if (gg >= GPIX) continue;
        int b2 = gg / NPIX;
        int r2 = gg - b2 * NPIX;
        float* obase = out + (size_t)(b2 * Sn + s) * (COUTc * NPIX) + r2;
        #pragma unroll
        for (int fm = 0; fm < 4; ++fm) {
            int cobase = wr * 64 + fm * 16 + (lane >> 4) * 4;
            #pragma unroll
            for (int j = 0; j < 4; ++j)
                obase[(cobase + j) * NPIX] = acc[fm][fn][j] + bias[fm][j];
        }
    }
}

// ---------------------------------------------------------------------------
extern "C" void kernel_launch(void* const* d_in, const int* in_sizes, int n_in,
                              void* d_out, int out_size, void* d_ws, size_t ws_size,
                              hipStream_t stream) {
    const float* x     = (const float*)d_in[0];
    const float* e     = (const float*)d_in[1];
    const float* mu_w  = (const float*)d_in[2];
    const float* rho_w = (const float*)d_in[3];
    const float* mu_b  = (const float*)d_in[4];
    const float* rho_b = (const float*)d_in[5];
    float* out = (float*)d_out;

    bf16*  wq       = (bf16*)d_ws;                          // 1,179,648 B
    float* bq       = (float*)((char*)d_ws + 1179648);      // 4,096 B
    float* partials = (float*)((char*)d_ws + 1183744);      // 8 B

    hipMemsetAsync(partials, 0, 2 * sizeof(float), stream);

    prep_kernel<<<dim3((Pc + 255) / 256), dim3(256), 0, stream>>>(
        e, mu_w, rho_w, mu_b, rho_b, wq, bq, partials);

    conv_mfma<<<dim3(NTILES, Sn), dim3(256), 0, stream>>>(x, wq, bq, out);

    finalize_kl<<<1, 1, 0, stream>>>(partials, out + (out_size - 1));
}

// Round 3
// 74.920 us; speedup vs baseline: 1.1714x; 1.1714x over previous
//
#include <hip/hip_runtime.h>
#include <hip/hip_bf16.h>
#include <math.h>

// Problem constants
#define Bn    8
#define Sn    8
#define CINc  64
#define Hh    32
#define Wwi   32
#define COUTc 128
#define PWc   73728
#define Pc    73856
#define WOc   30
#define NPIX  900      // 30*30 per (b,s)
#define GPIX  7200     // B*NPIX per s
#define KTOT  576      // CIN*3*3
#define NSTEP 9        // K-steps: one r = (ky,kx) each, 64 ci per step
#define PIXT  64
#define NTILES 113     // ceil(7200/64)

typedef __bf16 bf16;
typedef bf16  bf16x8 __attribute__((ext_vector_type(8)));
typedef float f32x4  __attribute__((ext_vector_type(4)));

__device__ __forceinline__ float softplus_f(float x) {
    return fmaxf(x, 0.f) + log1pf(expf(-fabsf(x)));
}

__device__ __forceinline__ unsigned int pack2(float a, float b) {
    unsigned short ua = __builtin_bit_cast(unsigned short, (bf16)a);
    unsigned short ub = __builtin_bit_cast(unsigned short, (bf16)b);
    return ((unsigned int)ub << 16) | (unsigned int)ua;
}

// ---------------------------------------------------------------------------
// Kernel A: sample weights (r-major layout for conv) + biases + KL partials.
// wq[((s*9 + r)*128 + co)*64 + ci] = mu_w[p] + softplus(rho_w[p])*e[s*P + p]
// with p = co*576 + ci*9 + r  (OIHW flatten).
// ---------------------------------------------------------------------------
__global__ __launch_bounds__(256) void prep_kernel(
        const float* __restrict__ e,
        const float* __restrict__ mu_w, const float* __restrict__ rho_w,
        const float* __restrict__ mu_b, const float* __restrict__ rho_b,
        bf16* __restrict__ wq, float* __restrict__ bq,
        float* __restrict__ partials) {
    int i = blockIdx.x * blockDim.x + threadIdx.x;
    float ls = 0.f, sq = 0.f;
    if (i < PWc) {
        int co  = i / 576;
        int rem = i - co * 576;
        int ci  = rem / 9;
        int r   = rem - ci * 9;
        int dst = (r * COUTc + co) * 64 + ci;
        float sig = softplus_f(rho_w[i]);
        ls = logf(sig);
        float mu = mu_w[i];
        #pragma unroll
        for (int s = 0; s < Sn; ++s) {
            float wv = fmaf(sig, e[s * Pc + i], mu);
            wq[s * PWc + dst] = (bf16)wv;
            sq += wv * wv;
        }
    } else if (i < Pc) {
        int c = i - PWc;
        float sig = softplus_f(rho_b[c]);
        ls = logf(sig);
        float mu = mu_b[c];
        #pragma unroll
        for (int s = 0; s < Sn; ++s) {
            float bv = fmaf(sig, e[s * Pc + i], mu);
            bq[s * COUTc + c] = bv;
            sq += bv * bv;
        }
    }
    #pragma unroll
    for (int off = 32; off > 0; off >>= 1) {
        ls += __shfl_down(ls, off);
        sq += __shfl_down(sq, off);
    }
    __shared__ float sls[4], ssq[4];
    int lane = threadIdx.x & 63, wid = threadIdx.x >> 6;
    if (lane == 0) { sls[wid] = ls; ssq[wid] = sq; }
    __syncthreads();
    if (threadIdx.x == 0) {
        atomicAdd(&partials[0], sls[0] + sls[1] + sls[2] + sls[3]);
        atomicAdd(&partials[1], ssq[0] + ssq[1] + ssq[2] + ssq[3]);
    }
}

__global__ void finalize_kl(const float* __restrict__ partials,
                            float* __restrict__ out_kl) {
    float kl = -partials[0] + 0.91893853320467274f * (float)(PWc + COUTc)
             + 0.5f * partials[1];
    *out_kl = kl;
}

// ---------------------------------------------------------------------------
// Kernel C: implicit-GEMM conv, r-major K order, BK=64 (one r per step).
// 1D grid, s = bid&7 (XCD-affine: all blocks of a sample land on one XCD,
// making that sample's x-slice (2.1 MB) and W-slice (147 KB) L2-resident).
// Block: 64 pixels x 128 co; 4 waves 2x2 (wave tile 64co x 32pix).
// LDS: Wl [128][64] bf16, Xl [64][64] bf16, XOR-swizzled 16B blocks
// (block ^= row&7) -> conflict-free b128 reads/writes. 24 KB total.
// Prefetch for step t+1 issued in compute phase of step t (regs), consumed
// by ds_write after the next WAR barrier.
// ---------------------------------------------------------------------------
__global__ __launch_bounds__(256) void conv_mfma(
        const float* __restrict__ xg, const bf16* __restrict__ wq,
        const float* __restrict__ bq, float* __restrict__ out) {
    const int bid  = blockIdx.x;
    const int s    = bid & 7;        // XCD-affine sample id
    const int tile = bid >> 3;
    const int t    = threadIdx.x;
    const int lane = t & 63;
    const int wid  = t >> 6;
    const int wr   = wid >> 1;   // co half (0/1)
    const int wc   = wid & 1;    // pix half (0/1)

    __shared__ bf16 Wl[COUTc * 64];   // 16 KB
    __shared__ bf16 Xl[PIXT * 64];    // 8 KB

    // ---- X gather: thread owns pix = t&63, ci chunk c2 = t>>6 (16 ci)
    const int pixl = t & 63;
    const int c2   = t >> 6;          // wave id, uniform per wave
    int g = tile * PIXT + pixl;
    if (g >= GPIX) g = GPIX - 1;      // clamp; garbage columns discarded at store
    const int bb = g / NPIX;
    const int rr = g - bb * NPIX;
    const int oy = rr / WOc;
    const int ox = rr - oy * WOc;
    const float* xpix = xg + ((size_t)(bb * Sn + s) << 16) + oy * Wwi + ox
                           + (size_t)c2 * 16 * 1024;
    bf16* xw0 = Xl + pixl * 64 + ((((c2 << 1) + 0) ^ (pixl & 7)) << 3);
    bf16* xw1 = Xl + pixl * 64 + ((((c2 << 1) + 1) ^ (pixl & 7)) << 3);

    // ---- W stage: thread owns cio = t&7 (16B block), rows co0 + 32*i
    const int cio = t & 7;
    const int co0 = t >> 3;           // 0..31
    const int wslot = (cio ^ (co0 & 7)) << 3;  // co&7 == co0&7 for co0+32i

    // ---- frag read addressing (loop-invariant)
    const int arow = lane & 15;
    const int sb   = lane >> 4;       // 0..3
    const int sx   = lane & 7;

    f32x4 acc[4][2];
    #pragma unroll
    for (int i = 0; i < 4; ++i)
        #pragma unroll
        for (int j = 0; j < 2; ++j)
            acc[i][j] = f32x4{0.f, 0.f, 0.f, 0.f};

    // ---- prologue: prefetch step 0
    float xr[16];
    uint4 wv4[4];
    {
        const bf16* wsp = wq + (size_t)(s * NSTEP) * (COUTc * 64);
        #pragma unroll
        for (int i = 0; i < 4; ++i)
            wv4[i] = *reinterpret_cast<const uint4*>(wsp + (co0 + 32 * i) * 64 + (cio << 3));
        #pragma unroll
        for (int j = 0; j < 16; ++j)
            xr[j] = xpix[j * 1024];
    }

    for (int step = 0; step < NSTEP; ++step) {
        __syncthreads();   // previous step's frag reads complete (WAR)

        // stage tiles from prefetched regs
        #pragma unroll
        for (int i = 0; i < 4; ++i)
            *reinterpret_cast<uint4*>(Wl + (co0 + 32 * i) * 64 + wslot) = wv4[i];
        uint4 v0, v1;
        v0.x = pack2(xr[0], xr[1]);  v0.y = pack2(xr[2], xr[3]);
        v0.z = pack2(xr[4], xr[5]);  v0.w = pack2(xr[6], xr[7]);
        v1.x = pack2(xr[8], xr[9]);  v1.y = pack2(xr[10], xr[11]);
        v1.z = pack2(xr[12], xr[13]); v1.w = pack2(xr[14], xr[15]);
        *reinterpret_cast<uint4*>(xw0) = v0;
        *reinterpret_cast<uint4*>(xw1) = v1;

        __syncthreads();   // tiles visible

        // prefetch step+1 during compute (drained at next barrier, hidden)
        if (step < NSTEP - 1) {
            int rn = step + 1;
            int ky = rn / 3;
            int roff = ky * Wwi + (rn - ky * 3);
            const bf16* wsp = wq + (size_t)(s * NSTEP + rn) * (COUTc * 64);
            #pragma unroll
            for (int i = 0; i < 4; ++i)
                wv4[i] = *reinterpret_cast<const uint4*>(wsp + (co0 + 32 * i) * 64 + (cio << 3));
            #pragma unroll
            for (int j = 0; j < 16; ++j)
                xr[j] = xpix[roff + j * 1024];
        }

        // fragments + MFMA: K=64 as two k-chunks of 32
        #pragma unroll
        for (int kk = 0; kk < 2; ++kk) {
            const int slot = (((kk << 2) + sb) ^ sx) << 3;
            bf16x8 af[4], bfv[2];
            #pragma unroll
            for (int fm = 0; fm < 4; ++fm)
                af[fm] = *reinterpret_cast<const bf16x8*>(
                    Wl + (wr * 64 + fm * 16 + arow) * 64 + slot);
            #pragma unroll
            for (int fn = 0; fn < 2; ++fn)
                bfv[fn] = *reinterpret_cast<const bf16x8*>(
                    Xl + (wc * 32 + fn * 16 + arow) * 64 + slot);
            #pragma unroll
            for (int fm = 0; fm < 4; ++fm)
                #pragma unroll
                for (int fn = 0; fn < 2; ++fn)
                    acc[fm][fn] = __builtin_amdgcn_mfma_f32_16x16x32_bf16(
                        af[fm], bfv[fn], acc[fm][fn], 0, 0, 0);
        }
    }

    // epilogue: D mapping col(pix)=lane&15, row(co)=(lane>>4)*4+reg
    float bias[4][4];
    #pragma unroll
    for (int fm = 0; fm < 4; ++fm)
        #pragma unroll
        for (int j = 0; j < 4; ++j)
            bias[fm][j] = bq[s * COUTc + wr * 64 + fm * 16 + (lane >> 4) * 4 + j];

    #pragma unroll
    for (int fn = 0; fn < 2; ++fn) {
        int pl = wc * 32 + fn * 16 + (lane & 15);
        int gg = tile * PIXT + pl;
        if (gg >= GPIX) continue;
        int b2 = gg / NPIX;
        int r2 = gg - b2 * NPIX;
        float* obase = out + (size_t)(b2 * Sn + s) * (COUTc * NPIX) + r2;
        #pragma unroll
        for (int fm = 0; fm < 4; ++fm) {
            int cobase = wr * 64 + fm * 16 + (lane >> 4) * 4;
            #pragma unroll
            for (int j = 0; j < 4; ++j)
                obase[(cobase + j) * NPIX] = acc[fm][fn][j] + bias[fm][j];
        }
    }
}

// ---------------------------------------------------------------------------
extern "C" void kernel_launch(void* const* d_in, const int* in_sizes, int n_in,
                              void* d_out, int out_size, void* d_ws, size_t ws_size,
                              hipStream_t stream) {
    const float* x     = (const float*)d_in[0];
    const float* e     = (const float*)d_in[1];
    const float* mu_w  = (const float*)d_in[2];
    const float* rho_w = (const float*)d_in[3];
    const float* mu_b  = (const float*)d_in[4];
    const float* rho_b = (const float*)d_in[5];
    float* out = (float*)d_out;

    bf16*  wq       = (bf16*)d_ws;                          // 1,179,648 B
    float* bq       = (float*)((char*)d_ws + 1179648);      // 4,096 B
    float* partials = (float*)((char*)d_ws + 1183744);      // 8 B

    hipMemsetAsync(partials, 0, 2 * sizeof(float), stream);

    prep_kernel<<<dim3((Pc + 255) / 256), dim3(256), 0, stream>>>(
        e, mu_w, rho_w, mu_b, rho_b, wq, bq, partials);

    conv_mfma<<<dim3(NTILES * Sn), dim3(256), 0, stream>>>(x, wq, bq, out);

    finalize_kl<<<1, 1, 0, stream>>>(partials, out + (out_size - 1));
}

// Round 4
// 50.426 us; speedup vs baseline: 1.7403x; 1.4857x over previous
//
#include <hip/hip_runtime.h>
#include <hip/hip_bf16.h>
#include <math.h>

// Problem constants
#define Bn    8
#define Sn    8
#define CINc  64
#define Hh    32
#define Wwi   32
#define COUTc 128
#define PWc   73728
#define Pc    73856
#define WOc   30
#define NPIX  900      // 30*30 per (b,s)
#define GPIX  7200     // B*NPIX per s
#define NSTEP 9        // one r=(ky,kx) per K-step, 64 ci each
#define PIXT  64
#define NTILES 113     // ceil(7200/64)

typedef __bf16 bf16;
typedef bf16  bf16x8 __attribute__((ext_vector_type(8)));
typedef float f32x4  __attribute__((ext_vector_type(4)));

__device__ __forceinline__ float softplus_f(float x) {
    return fmaxf(x, 0.f) + log1pf(expf(-fabsf(x)));
}

__device__ __forceinline__ unsigned int pack2(float a, float b) {
    unsigned short ua = __builtin_bit_cast(unsigned short, (bf16)a);
    unsigned short ub = __builtin_bit_cast(unsigned short, (bf16)b);
    return ((unsigned int)ub << 16) | (unsigned int)ua;
}

// global->LDS direct copy, 16B per lane. LDS dest = uniform base + lane*16
// (implicit); global src is per-lane.
__device__ __forceinline__ void gl16(const void* g, void* l) {
    typedef __attribute__((address_space(1))) void gvoid;
    typedef __attribute__((address_space(3))) void lvoid;
    __builtin_amdgcn_global_load_lds((gvoid*)g, (lvoid*)l, 16, 0, 0);
}

// ---------------------------------------------------------------------------
// Kernel X: x (fp32, [img=b*8+s][ci][y][x]) -> xt (bf16, [img][y][x][ci]).
// Channels-last so 8 consecutive ci = 16 B, ready for global_load_lds.
// ---------------------------------------------------------------------------
__global__ __launch_bounds__(256) void xcast_kernel(
        const float* __restrict__ xg, bf16* __restrict__ xt) {
    const int blk  = blockIdx.x;      // 512 blocks: img*8 + part
    const int img  = blk >> 3;
    const int part = blk & 7;
    const int t    = threadIdx.x;
    const int p    = part * 128 + (t >> 1);  // yx position 0..1023
    const int half = t & 1;                  // which 32 ci

    const float* src = xg + ((size_t)img << 16) + (size_t)(half * 32) * 1024 + p;
    bf16*        dst = xt + ((size_t)img << 16) + (size_t)p * 64 + half * 32;

    #pragma unroll
    for (int o = 0; o < 4; ++o) {
        uint4 pk;
        pk.x = pack2(src[(o * 8 + 0) * 1024], src[(o * 8 + 1) * 1024]);
        pk.y = pack2(src[(o * 8 + 2) * 1024], src[(o * 8 + 3) * 1024]);
        pk.z = pack2(src[(o * 8 + 4) * 1024], src[(o * 8 + 5) * 1024]);
        pk.w = pack2(src[(o * 8 + 6) * 1024], src[(o * 8 + 7) * 1024]);
        *reinterpret_cast<uint4*>(dst + o * 8) = pk;
    }
}

// ---------------------------------------------------------------------------
// Kernel A: sample weights into the per-(s,step) LDS byte image (16 KB each,
// XOR swizzle baked in) + biases + KL partials.
// Image byte layout: co*128 + ((ci>>3) ^ (co&7))*16 + (ci&7)*2.
// ---------------------------------------------------------------------------
__global__ __launch_bounds__(256) void prep_kernel(
        const float* __restrict__ e,
        const float* __restrict__ mu_w, const float* __restrict__ rho_w,
        const float* __restrict__ mu_b, const float* __restrict__ rho_b,
        bf16* __restrict__ wimg, float* __restrict__ bq,
        float* __restrict__ partials) {
    int i = blockIdx.x * blockDim.x + threadIdx.x;
    float ls = 0.f, sq = 0.f;
    if (i < PWc) {
        int co  = i / 576;
        int rem = i - co * 576;
        int ci  = rem / 9;
        int r   = rem - ci * 9;
        // element index within wimg (bf16 units)
        int dst = (r << 13) + (co << 6) + ((((ci >> 3) ^ (co & 7)) << 3) | (ci & 7));
        float sig = softplus_f(rho_w[i]);
        ls = logf(sig);
        float mu = mu_w[i];
        #pragma unroll
        for (int s = 0; s < Sn; ++s) {
            float wv = fmaf(sig, e[s * Pc + i], mu);
            wimg[(size_t)s * (NSTEP * 8192) + dst] = (bf16)wv;
            sq += wv * wv;
        }
    } else if (i < Pc) {
        int c = i - PWc;
        float sig = softplus_f(rho_b[c]);
        ls = logf(sig);
        float mu = mu_b[c];
        #pragma unroll
        for (int s = 0; s < Sn; ++s) {
            float bv = fmaf(sig, e[s * Pc + i], mu);
            bq[s * COUTc + c] = bv;
            sq += bv * bv;
        }
    }
    #pragma unroll
    for (int off = 32; off > 0; off >>= 1) {
        ls += __shfl_down(ls, off);
        sq += __shfl_down(sq, off);
    }
    __shared__ float sls[4], ssq[4];
    int lane = threadIdx.x & 63, wid = threadIdx.x >> 6;
    if (lane == 0) { sls[wid] = ls; ssq[wid] = sq; }
    __syncthreads();
    if (threadIdx.x == 0) {
        atomicAdd(&partials[0], sls[0] + sls[1] + sls[2] + sls[3]);
        atomicAdd(&partials[1], ssq[0] + ssq[1] + ssq[2] + ssq[3]);
    }
}

__global__ void finalize_kl(const float* __restrict__ partials,
                            float* __restrict__ out_kl) {
    float kl = -partials[0] + 0.91893853320467274f * (float)(PWc + COUTc)
             + 0.5f * partials[1];
    *out_kl = kl;
}

// ---------------------------------------------------------------------------
// Kernel C: implicit-GEMM conv. 2-phase double-buffered schedule, all staging
// via global_load_lds (6 wave-issues/step), swizzle pre-baked in the sources.
// 1D grid, s = bid&7 (XCD-affine). Block: 64 pix x 128 co, 4 waves 2x2.
// LDS: 2 x (16 KB W + 8 KB X) = 48 KB.
// ---------------------------------------------------------------------------
__global__ __launch_bounds__(256) void conv_mfma(
        const bf16* __restrict__ xt, const bf16* __restrict__ wimg,
        const float* __restrict__ bq, float* __restrict__ out) {
    const int bid  = blockIdx.x;
    const int s    = bid & 7;
    const int tile = bid >> 3;
    const int t    = threadIdx.x;
    const int lane = t & 63;
    const int w    = t >> 6;
    const int wr   = w >> 1;     // co half (0/1)
    const int wc   = w & 1;      // pix half (0/1)

    __shared__ bf16 Wbuf[2][COUTc * 64];   // 2 x 16 KB
    __shared__ bf16 Xbuf[2][PIXT * 64];    // 2 x 8 KB

    // ---- W staging source (per-lane address; image is lane-linear)
    const char* wsrcB = (const char*)wimg + ((size_t)(s * NSTEP) << 14)
                      + (w << 12) + (lane << 4);

    // ---- X staging sources: wave w stages pix w*16 .. w*16+15
    const int m = lane & 7;                // ci-octet slot this lane fills
    const char* xsrc0; const char* xsrc1;
    {
        int pix0 = w * 16 + (lane >> 3);
        #pragma unroll
        for (int i = 0; i < 2; ++i) {
            int pixl = pix0 + i * 8;
            int g = tile * PIXT + pixl;
            if (g >= GPIX) g = GPIX - 1;   // clamp; garbage cols discarded
            int bb = g / NPIX;
            int rr = g - bb * NPIX;
            int oy = rr / WOc;
            int ox = rr - oy * WOc;
            const char* p = (const char*)xt
                + ((((size_t)(bb * Sn + s) << 10) + oy * Wwi + ox) << 7)
                + ((m ^ (pixl & 7)) << 4);
            if (i == 0) xsrc0 = p; else xsrc1 = p;
        }
    }

    // ---- frag read addressing (loop-invariant)
    const int arow = lane & 15;
    const int sb   = lane >> 4;
    const int sx   = lane & 7;

    f32x4 acc[4][2];
    #pragma unroll
    for (int i = 0; i < 4; ++i)
        #pragma unroll
        for (int j = 0; j < 2; ++j)
            acc[i][j] = f32x4{0.f, 0.f, 0.f, 0.f};

    // ---- stage helper (macro to keep literal size arg)
    #define STAGE(stepn, b)                                                  \
    {                                                                        \
        const char* ws = wsrcB + ((stepn) << 14);                            \
        char* wl = (char*)(&Wbuf[(b)][0]) + (w << 12);                       \
        gl16(ws,        wl);                                                 \
        gl16(ws + 1024, wl + 1024);                                          \
        gl16(ws + 2048, wl + 2048);                                          \
        gl16(ws + 3072, wl + 3072);                                          \
        int ky_ = (stepn) / 3;                                               \
        int roffB_ = ((ky_ * Wwi + ((stepn) - 3 * ky_)) << 7);               \
        char* xl = (char*)(&Xbuf[(b)][0]) + (w << 11);                       \
        gl16(xsrc0 + roffB_, xl);                                            \
        gl16(xsrc1 + roffB_, xl + 1024);                                     \
    }

    // ---- prologue: stage step 0 into buf 0
    STAGE(0, 0);
    asm volatile("s_waitcnt vmcnt(0)" ::: "memory");
    __syncthreads();

    int buf = 0;
    for (int step = 0; step < NSTEP; ++step) {
        if (step < NSTEP - 1) STAGE(step + 1, buf ^ 1);

        const bf16* Wl = &Wbuf[buf][0];
        const bf16* Xl = &Xbuf[buf][0];
        #pragma unroll
        for (int kk = 0; kk < 2; ++kk) {
            const int slot = (((kk << 2) + sb) ^ sx) << 3;
            bf16x8 af[4], bfv[2];
            #pragma unroll
            for (int fm = 0; fm < 4; ++fm)
                af[fm] = *reinterpret_cast<const bf16x8*>(
                    Wl + (wr * 64 + fm * 16 + arow) * 64 + slot);
            #pragma unroll
            for (int fn = 0; fn < 2; ++fn)
                bfv[fn] = *reinterpret_cast<const bf16x8*>(
                    Xl + (wc * 32 + fn * 16 + arow) * 64 + slot);
            #pragma unroll
            for (int fm = 0; fm < 4; ++fm)
                #pragma unroll
                for (int fn = 0; fn < 2; ++fn)
                    acc[fm][fn] = __builtin_amdgcn_mfma_f32_16x16x32_bf16(
                        af[fm], bfv[fn], acc[fm][fn], 0, 0, 0);
        }

        asm volatile("s_waitcnt vmcnt(0)" ::: "memory");
        __syncthreads();
        buf ^= 1;
    }
    #undef STAGE

    // ---- epilogue: D mapping col(pix)=lane&15, row(co)=(lane>>4)*4+reg
    float bias[4][4];
    #pragma unroll
    for (int fm = 0; fm < 4; ++fm)
        #pragma unroll
        for (int j = 0; j < 4; ++j)
            bias[fm][j] = bq[s * COUTc + wr * 64 + fm * 16 + (lane >> 4) * 4 + j];

    #pragma unroll
    for (int fn = 0; fn < 2; ++fn) {
        int pl = wc * 32 + fn * 16 + (lane & 15);
        int gg = tile * PIXT + pl;
        if (gg >= GPIX) continue;
        int b2 = gg / NPIX;
        int r2 = gg - b2 * NPIX;
        float* obase = out + (size_t)(b2 * Sn + s) * (COUTc * NPIX) + r2;
        #pragma unroll
        for (int fm = 0; fm < 4; ++fm) {
            int cobase = wr * 64 + fm * 16 + (lane >> 4) * 4;
            #pragma unroll
            for (int j = 0; j < 4; ++j)
                obase[(cobase + j) * NPIX] = acc[fm][fn][j] + bias[fm][j];
        }
    }
}

// ---------------------------------------------------------------------------
extern "C" void kernel_launch(void* const* d_in, const int* in_sizes, int n_in,
                              void* d_out, int out_size, void* d_ws, size_t ws_size,
                              hipStream_t stream) {
    const float* x     = (const float*)d_in[0];
    const float* e     = (const float*)d_in[1];
    const float* mu_w  = (const float*)d_in[2];
    const float* rho_w = (const float*)d_in[3];
    const float* mu_b  = (const float*)d_in[4];
    const float* rho_b = (const float*)d_in[5];
    float* out = (float*)d_out;

    // workspace layout
    bf16*  wimg     = (bf16*)d_ws;                            // 1,179,648 B
    float* bq       = (float*)((char*)d_ws + 1179648);        // 4,096 B
    float* partials = (float*)((char*)d_ws + 1183744);        // 8 B
    bf16*  xt       = (bf16*)((char*)d_ws + 1184256);         // 8,388,608 B

    hipMemsetAsync(partials, 0, 2 * sizeof(float), stream);

    xcast_kernel<<<dim3(512), dim3(256), 0, stream>>>(x, xt);

    prep_kernel<<<dim3((Pc + 255) / 256), dim3(256), 0, stream>>>(
        e, mu_w, rho_w, mu_b, rho_b, wimg, bq, partials);

    conv_mfma<<<dim3(NTILES * Sn), dim3(256), 0, stream>>>(xt, wimg, bq, out);

    finalize_kl<<<1, 1, 0, stream>>>(partials, out + (out_size - 1));
}

// Round 5
// 30.226 us; speedup vs baseline: 2.9035x; 1.6683x over previous
//
#include <hip/hip_runtime.h>
#include <hip/hip_bf16.h>
#include <math.h>

// Problem constants
#define Bn    8
#define Sn    8
#define COUTc 128
#define PWc   73728
#define Pc    73856
#define WOc   30
#define NPIX  900      // 30*30 per (b,s)
#define GPIX  7200     // B*NPIX per s
#define NSTEP 9        // one r=(ky,kx) per K-step, 64 ci each
#define TILE  128      // pixels per block
#define NT2   57       // ceil(7200/128)

typedef __bf16 bf16;
typedef bf16  bf16x8 __attribute__((ext_vector_type(8)));
typedef float f32x16 __attribute__((ext_vector_type(16)));

__device__ __forceinline__ float softplus_f(float x) {
    return fmaxf(x, 0.f) + log1pf(expf(-fabsf(x)));
}

__device__ __forceinline__ unsigned int pack2(float a, float b) {
    unsigned short ua = __builtin_bit_cast(unsigned short, (bf16)a);
    unsigned short ub = __builtin_bit_cast(unsigned short, (bf16)b);
    return ((unsigned int)ub << 16) | (unsigned int)ua;
}

// global->LDS direct copy, 16B per lane. LDS dest = wave-uniform base
// (+ implicit lane*16); global src is per-lane.
__device__ __forceinline__ void gl16(const void* g, void* l) {
    typedef __attribute__((address_space(1))) void gvoid;
    typedef __attribute__((address_space(3))) void lvoid;
    __builtin_amdgcn_global_load_lds((gvoid*)g, (lvoid*)l, 16, 0, 0);
}

// ---------------------------------------------------------------------------
// Kernel 1 (fused): blocks 0..511 = xcast (x fp32 NCHW -> xt bf16 NHWC),
// blocks 512..799 = W sampling into swizzled per-(s,r) LDS images,
// block 800 = bias sampling. Prep blocks write KL partials to slots[289]
// unconditionally (no memset needed).
// wimg page (s,r): element (co<<6) + (((ci>>3)^(co&7))<<3) + (ci&7).
// ---------------------------------------------------------------------------
__global__ __launch_bounds__(256) void prep_all(
        const float* __restrict__ xg, const float* __restrict__ e,
        const float* __restrict__ mu_w, const float* __restrict__ rho_w,
        const float* __restrict__ mu_b, const float* __restrict__ rho_b,
        bf16* __restrict__ xt, bf16* __restrict__ wimg,
        float* __restrict__ bq, float* __restrict__ slots) {
    const int bid = blockIdx.x;
    const int t   = threadIdx.x;

    if (bid < 512) {  // ---- xcast
        const int img  = bid >> 3;
        const int part = bid & 7;
        const int p    = part * 128 + (t >> 1);
        const int half = t & 1;
        const float* src = xg + ((size_t)img << 16) + (size_t)(half * 32) * 1024 + p;
        bf16*        dst = xt + ((size_t)img << 16) + (size_t)p * 64 + half * 32;
        #pragma unroll
        for (int o = 0; o < 4; ++o) {
            uint4 pk;
            pk.x = pack2(src[(o * 8 + 0) * 1024], src[(o * 8 + 1) * 1024]);
            pk.y = pack2(src[(o * 8 + 2) * 1024], src[(o * 8 + 3) * 1024]);
            pk.z = pack2(src[(o * 8 + 4) * 1024], src[(o * 8 + 5) * 1024]);
            pk.w = pack2(src[(o * 8 + 6) * 1024], src[(o * 8 + 7) * 1024]);
            *reinterpret_cast<uint4*>(dst + o * 8) = pk;
        }
        return;
    }

    float ls = 0.f, sq = 0.f;
    if (bid < 800) {  // ---- W prep: block = (r, chunk of 256 (co,ci) pairs)
        const int rb    = bid - 512;
        const int r     = rb >> 5;
        const int chunk = rb & 31;
        const int idx   = chunk * 256 + t;   // 0..8191
        const int co    = idx >> 6;
        const int ci    = idx & 63;
        const int p     = co * 576 + ci * 9 + r;
        float sig = softplus_f(rho_w[p]);
        ls = logf(sig);
        float mu = mu_w[p];
        const int dstp = (co << 6) + (((ci >> 3) ^ (co & 7)) << 3) + (ci & 7);
        #pragma unroll
        for (int s = 0; s < Sn; ++s) {
            float wv = fmaf(sig, e[s * Pc + p], mu);
            wimg[((s * NSTEP + r) << 13) + dstp] = (bf16)wv;
            sq += wv * wv;
        }
    } else {          // ---- bias prep (bid == 800)
        if (t < COUTc) {
            float sig = softplus_f(rho_b[t]);
            ls = logf(sig);
            float mu = mu_b[t];
            #pragma unroll
            for (int s = 0; s < Sn; ++s) {
                float bv = fmaf(sig, e[s * Pc + PWc + t], mu);
                bq[s * COUTc + t] = bv;
                sq += bv * bv;
            }
        }
    }

    #pragma unroll
    for (int off = 32; off > 0; off >>= 1) {
        ls += __shfl_down(ls, off);
        sq += __shfl_down(sq, off);
    }
    __shared__ float sls[4], ssq[4];
    const int lane = t & 63, wd = t >> 6;
    if (lane == 0) { sls[wd] = ls; ssq[wd] = sq; }
    __syncthreads();
    if (t == 0) {
        slots[2 * (bid - 512)]     = sls[0] + sls[1] + sls[2] + sls[3];
        slots[2 * (bid - 512) + 1] = ssq[0] + ssq[1] + ssq[2] + ssq[3];
    }
}

// ---------------------------------------------------------------------------
// Kernel 2: implicit-GEMM conv. Block = 128co x 128pix, 4 waves (2x2 of
// 64x64 wave tiles), mfma_f32_32x32x16_bf16, BK=64 (one r per step).
// Double-buffered LDS (64 KB), all staging via global_load_lds with the
// XOR swizzle pre-baked into the global sources. Counted vmcnt(8) + raw
// s_barrier (T3/T4); last iteration peeled with vmcnt(0).
// s = bid&7 -> XCD-affine; KL finalize folded into block 0.
// ---------------------------------------------------------------------------
__global__ __launch_bounds__(256) void conv_mfma(
        const bf16* __restrict__ xt, const bf16* __restrict__ wimg,
        const float* __restrict__ bq, const float* __restrict__ slots,
        float* __restrict__ out, float* __restrict__ klout) {
    const int bid  = blockIdx.x;
    const int s    = bid & 7;
    const int tile = bid >> 3;
    const int t    = threadIdx.x;
    const int lane = t & 63;
    const int w    = t >> 6;
    const int wr   = w >> 1;     // co half (0/1)
    const int wc   = w & 1;      // pix half (0/1)

    __shared__ bf16 Wbuf[2][8192];   // 2 x 16 KB  [co 0..127][ci-oct swz]
    __shared__ bf16 Xbuf[2][8192];   // 2 x 16 KB  [pix 0..127][ci-oct swz]

    // W staging source: wimg page is the exact LDS byte image
    const char* wsrcL = (const char*)wimg + ((size_t)(s * NSTEP) << 14)
                      + (w << 12) + (lane << 4);

    // X staging sources: wave w stages pix w*32 .. w*32+31, 4 chunks
    const char *x0, *x1, *x2, *x3;
    #pragma unroll
    for (int q = 0; q < 4; ++q) {
        int pix = w * 32 + q * 8 + (lane >> 3);
        int g   = tile * TILE + pix;
        if (g >= GPIX) g = GPIX - 1;      // clamp; garbage cols discarded
        int b2 = g / NPIX;
        int rr = g - b2 * NPIX;
        int oy = rr / WOc;
        int ox = rr - oy * WOc;
        int m  = (lane & 7) ^ (pix & 7);  // source ci-octet for this slot
        const char* ptr = (const char*)xt
            + ((((size_t)(b2 * Sn + s) << 10) + oy * 32 + ox) << 7) + (m << 4);
        if (q == 0) x0 = ptr; else if (q == 1) x1 = ptr;
        else if (q == 2) x2 = ptr; else x3 = ptr;
    }

    f32x16 acc[2][2];
    #pragma unroll
    for (int i = 0; i < 2; ++i)
        #pragma unroll
        for (int j = 0; j < 2; ++j)
            #pragma unroll
            for (int k = 0; k < 16; ++k)
                acc[i][j][k] = 0.f;

    #define STAGE(stepc, b)                                                  \
    {                                                                        \
        const char* ws_ = wsrcL + ((stepc) << 14);                           \
        char* wl_ = (char*)(&Wbuf[(b)][0]) + (w << 12);                      \
        gl16(ws_,        wl_);                                               \
        gl16(ws_ + 1024, wl_ + 1024);                                        \
        gl16(ws_ + 2048, wl_ + 2048);                                        \
        gl16(ws_ + 3072, wl_ + 3072);                                        \
        const int roff_ = (((stepc) / 3) * 32 + ((stepc) % 3)) * 128;        \
        char* xl_ = (char*)(&Xbuf[(b)][0]) + (w << 12);                      \
        gl16(x0 + roff_, xl_);                                               \
        gl16(x1 + roff_, xl_ + 1024);                                        \
        gl16(x2 + roff_, xl_ + 2048);                                        \
        gl16(x3 + roff_, xl_ + 3072);                                        \
    }

    #define COMPUTE(b)                                                       \
    {                                                                        \
        const bf16* Wl_ = &Wbuf[(b)][0];                                     \
        const bf16* Xl_ = &Xbuf[(b)][0];                                     \
        _Pragma("unroll")                                                    \
        for (int kc = 0; kc < 4; ++kc) {                                     \
            const int oct_ = ((kc << 1) + (lane >> 5)) ^ (lane & 7);         \
            bf16x8 af0 = *reinterpret_cast<const bf16x8*>(                   \
                Wl_ + ((wr * 64 + (lane & 31)) << 6) + (oct_ << 3));         \
            bf16x8 af1 = *reinterpret_cast<const bf16x8*>(                   \
                Wl_ + ((wr * 64 + 32 + (lane & 31)) << 6) + (oct_ << 3));    \
            bf16x8 bf0 = *reinterpret_cast<const bf16x8*>(                   \
                Xl_ + ((wc * 64 + (lane & 31)) << 6) + (oct_ << 3));         \
            bf16x8 bf1 = *reinterpret_cast<const bf16x8*>(                   \
                Xl_ + ((wc * 64 + 32 + (lane & 31)) << 6) + (oct_ << 3));    \
            acc[0][0] = __builtin_amdgcn_mfma_f32_32x32x16_bf16(af0, bf0, acc[0][0], 0, 0, 0); \
            acc[0][1] = __builtin_amdgcn_mfma_f32_32x32x16_bf16(af0, bf1, acc[0][1], 0, 0, 0); \
            acc[1][0] = __builtin_amdgcn_mfma_f32_32x32x16_bf16(af1, bf0, acc[1][0], 0, 0, 0); \
            acc[1][1] = __builtin_amdgcn_mfma_f32_32x32x16_bf16(af1, bf1, acc[1][1], 0, 0, 0); \
        }                                                                    \
    }

    // prologue: two stages in flight
    STAGE(0, 0);
    STAGE(1, 1);

    #define ITER(tt, b)                                                      \
        asm volatile("s_waitcnt vmcnt(8)" ::: "memory");                     \
        __builtin_amdgcn_s_barrier();                                        \
        __builtin_amdgcn_sched_barrier(0);                                   \
        COMPUTE(b);                                                          \
        __builtin_amdgcn_sched_barrier(0);                                   \
        __builtin_amdgcn_s_barrier();                                        \
        STAGE((tt) + 2, b);

    ITER(0, 0)
    ITER(1, 1)
    ITER(2, 0)
    ITER(3, 1)
    ITER(4, 0)
    ITER(5, 1)
    ITER(6, 0)
    // t = 7 (buf 1): no further stage
    asm volatile("s_waitcnt vmcnt(8)" ::: "memory");
    __builtin_amdgcn_s_barrier();
    __builtin_amdgcn_sched_barrier(0);
    COMPUTE(1);
    // t = 8 (buf 0): final, drain
    asm volatile("s_waitcnt vmcnt(0)" ::: "memory");
    __builtin_amdgcn_s_barrier();
    __builtin_amdgcn_sched_barrier(0);
    COMPUTE(0);

    #undef ITER
    #undef COMPUTE
    #undef STAGE

    // ---- epilogue: 32x32 C/D: col(pix)=lane&31, row(co)=(reg&3)+8*(reg>>2)+4*(lane>>5)
    const int colp = lane & 31;
    const int hi   = lane >> 5;
    #pragma unroll
    for (int ti = 0; ti < 2; ++ti) {
        float bs[16];
        #pragma unroll
        for (int reg = 0; reg < 16; ++reg) {
            int co = wr * 64 + ti * 32 + (reg & 3) + 8 * (reg >> 2) + 4 * hi;
            bs[reg] = bq[s * COUTc + co];
        }
        #pragma unroll
        for (int tj = 0; tj < 2; ++tj) {
            int gg = tile * TILE + wc * 64 + tj * 32 + colp;
            if (gg >= GPIX) continue;
            int b2 = gg / NPIX;
            int r2 = gg - b2 * NPIX;
            float* ob = out + (size_t)(b2 * Sn + s) * (COUTc * NPIX) + r2;
            #pragma unroll
            for (int reg = 0; reg < 16; ++reg) {
                int co = wr * 64 + ti * 32 + (reg & 3) + 8 * (reg >> 2) + 4 * hi;
                ob[co * NPIX] = acc[ti][tj][reg] + bs[reg];
            }
        }
    }

    // ---- KL finalize (block 0, wave 0): sum the 289 partial slots
    if (bid == 0 && w == 0) {
        float ls = 0.f, sq = 0.f;
        for (int i = lane; i < 289; i += 64) {
            ls += slots[2 * i];
            sq += slots[2 * i + 1];
        }
        #pragma unroll
        for (int off = 32; off > 0; off >>= 1) {
            ls += __shfl_down(ls, off);
            sq += __shfl_down(sq, off);
        }
        if (lane == 0)
            *klout = -ls + 0.91893853320467274f * (float)Pc + 0.5f * sq;
    }
}

// ---------------------------------------------------------------------------
extern "C" void kernel_launch(void* const* d_in, const int* in_sizes, int n_in,
                              void* d_out, int out_size, void* d_ws, size_t ws_size,
                              hipStream_t stream) {
    const float* x     = (const float*)d_in[0];
    const float* e     = (const float*)d_in[1];
    const float* mu_w  = (const float*)d_in[2];
    const float* rho_w = (const float*)d_in[3];
    const float* mu_b  = (const float*)d_in[4];
    const float* rho_b = (const float*)d_in[5];
    float* out = (float*)d_out;

    // workspace layout
    bf16*  wimg  = (bf16*)d_ws;                         // 1,179,648 B
    float* bq    = (float*)((char*)d_ws + 1179648);     // 4,096 B
    float* slots = (float*)((char*)d_ws + 1183744);     // 2,312 B (pad to 4K)
    bf16*  xt    = (bf16*)((char*)d_ws + 1187840);      // 8,388,608 B

    prep_all<<<dim3(801), dim3(256), 0, stream>>>(
        x, e, mu_w, rho_w, mu_b, rho_b, xt, wimg, bq, slots);

    conv_mfma<<<dim3(NT2 * Sn), dim3(256), 0, stream>>>(
        xt, wimg, bq, slots, out, out + (out_size - 1));
}